// Round 9
// baseline (115.218 us; speedup 1.0000x reference)
//
#include <hip/hip_runtime.h>
#include <stdint.h>

// Problem constants
#define B_ 4
#define T_ 1024
#define D_ 1024
#define H_ 2048
#define E_ 8

// Device-coherent relaxed atomics (bypass non-coherent per-XCD L2 for our
// small inter-phase buffers; NO fences -> no L2 writebacks).
#define AL(p)    __hip_atomic_load((p), __ATOMIC_RELAXED, __HIP_MEMORY_SCOPE_AGENT)
#define AS(p, v) __hip_atomic_store((p), (v), __ATOMIC_RELAXED, __HIP_MEMORY_SCOPE_AGENT)

// Fire-and-forget global->LDS staging, 16B/lane. LDS dest wave-uniform.
__device__ __forceinline__ void stage16(const float* g, float* l) {
    __builtin_amdgcn_global_load_lds(
        (const __attribute__((address_space(1))) uint32_t*)g,
        (__attribute__((address_space(3))) uint32_t*)l, 16, 0, 0);
}

// ---------------------------------------------------------------------------
// Fused kernel: 512 blocks x 256 thr, all co-resident (48 KB LDS, lb(256,2)).
//  A: w2sum[r] = sum_d w2[r,d]          (32 rows/block, rolling 3-buf pipe)
//  B: vT[d*E+e] = w1[e,d,:].w2sum[e,:]  (16 rows/block, same pipe, half-rows)
//  C: gating + collapsed expert sum -> s[n]   (8 tokens/block)
//  D: log-softmax over T per batch row  (last block)
// Sync: per-thread vmcnt(0) drain + __syncthreads + relaxed agent atomicAdd;
// B waits per-expert (ecnt[e]==64) so it overlaps A's remaining experts.
// ---------------------------------------------------------------------------
__global__ __launch_bounds__(256, 2) void fused_kernel(
    const float* __restrict__ x,  const float* __restrict__ wg,
    const float* __restrict__ w1, const float* __restrict__ b1,
    const float* __restrict__ w2, const float* __restrict__ b2,
    float* __restrict__ w2sum, float* __restrict__ vT,
    float* __restrict__ cbuf,  float* __restrict__ sbuf,
    unsigned* __restrict__ ecnt, unsigned* __restrict__ bcnt,
    unsigned* __restrict__ ccnt, float* __restrict__ out)
{
    __shared__ float buf[3][4096];                 // 48 KB, 16 KB tiles
    const int b    = blockIdx.x;                   // 0..511
    const int wid  = threadIdx.x >> 6;
    const int lane = threadIdx.x & 63;
    const int e    = b >> 6;                       // expert (64 blocks/expert)

    // ====================== Phase A: w2 row sums ======================
    {
        const float* src = w2 + ((size_t)b * 32 + wid) * D_ + lane * 4;
#define ASTG(k) { const float* s_ = src + (size_t)(k) * 4 * D_;               \
                  float* d_ = &buf[(k) % 3][wid * 1024];                      \
                  stage16(s_, d_);         stage16(s_ + 256, d_ + 256);       \
                  stage16(s_ + 512, d_ + 512); stage16(s_ + 768, d_ + 768); }
        ASTG(0); ASTG(1);
        float accs[8];
#pragma unroll
        for (int k = 0; k < 8; ++k) {
            if (k < 7) asm volatile("s_waitcnt vmcnt(4)" ::: "memory");
            else       asm volatile("s_waitcnt vmcnt(0)" ::: "memory");
            if (k < 6) ASTG(k + 2);
            const float* row = &buf[k % 3][wid * 1024];
            float acc = 0.f;
#pragma unroll
            for (int j = 0; j < 4; ++j) {
                float4 a = *(const float4*)&row[j * 256 + lane * 4];
                acc += a.x + a.y + a.z + a.w;
            }
#pragma unroll
            for (int off = 32; off >= 1; off >>= 1) acc += __shfl_xor(acc, off, 64);
            accs[k] = acc;
        }
#undef ASTG
        if (lane == 0) {
#pragma unroll
            for (int k = 0; k < 8; ++k)
                AS(&w2sum[(size_t)b * 32 + k * 4 + wid], accs[k]);
        }
        asm volatile("s_waitcnt vmcnt(0)" ::: "memory");
        __syncthreads();
        if (threadIdx.x == 0)
            __hip_atomic_fetch_add(&ecnt[e], 1u, __ATOMIC_RELAXED, __HIP_MEMORY_SCOPE_AGENT);
    }

    // ====================== Phase B: v build ======================
    {
        if (threadIdx.x == 0)
            while (AL(&ecnt[e]) < 64u) __builtin_amdgcn_s_sleep(2);
        __syncthreads();

        // w2sum[e] fragment -> 8 float4 regs via coherent scalar loads
        const float* wsr = w2sum + (size_t)e * H_;
        float4 W[8];
#pragma unroll
        for (int m = 0; m < 8; ++m) {
            W[m].x = AL(wsr + m * 256 + lane * 4 + 0);
            W[m].y = AL(wsr + m * 256 + lane * 4 + 1);
            W[m].z = AL(wsr + m * 256 + lane * 4 + 2);
            W[m].w = AL(wsr + m * 256 + lane * 4 + 3);
        }
        asm volatile("s_waitcnt vmcnt(0)" ::: "memory");   // vmcnt clean

        const int d0 = (b & 63) * 16;
        const float* bsrc = w1 + ((size_t)e * D_ + d0 + wid) * H_ + lane * 4;
        // tile t = (rg = t>>1, half h = t&1): 4KB/wave slice of rows d0+rg*4+wid
#define BSTG(t) { const float* s_ = bsrc + (size_t)((t) >> 1) * 4 * H_ + ((t) & 1) * 1024; \
                  float* d_ = &buf[(t) % 3][wid * 1024];                      \
                  stage16(s_, d_);         stage16(s_ + 256, d_ + 256);       \
                  stage16(s_ + 512, d_ + 512); stage16(s_ + 768, d_ + 768); }
        BSTG(0); BSTG(1);
        float bacc[4] = {0.f, 0.f, 0.f, 0.f};
#pragma unroll
        for (int t = 0; t < 8; ++t) {
            if (t < 7) asm volatile("s_waitcnt vmcnt(4)" ::: "memory");
            else       asm volatile("s_waitcnt vmcnt(0)" ::: "memory");
            if (t < 6) BSTG(t + 2);
            const float* row = &buf[t % 3][wid * 1024];
            const int h4 = (t & 1) * 4;
            float a = 0.f;
#pragma unroll
            for (int j = 0; j < 4; ++j) {
                float4 av = *(const float4*)&row[j * 256 + lane * 4];
                float4 wv = W[h4 + j];
                a += av.x * wv.x + av.y * wv.y + av.z * wv.z + av.w * wv.w;
            }
            bacc[t >> 1] += a;
        }
#undef BSTG
#pragma unroll
        for (int rg = 0; rg < 4; ++rg) {
#pragma unroll
            for (int off = 32; off >= 1; off >>= 1)
                bacc[rg] += __shfl_xor(bacc[rg], off, 64);
        }
        if (lane == 0) {
#pragma unroll
            for (int rg = 0; rg < 4; ++rg)
                AS(&vT[(size_t)(d0 + rg * 4 + wid) * E_ + e], bacc[rg]);
        }

        // c[e] = b1[e,:].w2sum[e,:] + sum_d b2[e,d]  (W regs still live)
        if ((b & 63) == 0 && wid == 0) {
            const float4* bp = (const float4*)(b1 + (size_t)e * H_) + lane;
            float s = 0.f;
#pragma unroll
            for (int m = 0; m < 8; ++m) {
                float4 q = bp[m * 64];
                float4 wv = W[m];
                s += q.x * wv.x + q.y * wv.y + q.z * wv.z + q.w * wv.w;
            }
            const float4* cp = (const float4*)(b2 + (size_t)e * D_) + lane;
#pragma unroll
            for (int j = 0; j < 4; ++j) {
                float4 bb = cp[j * 64];
                s += bb.x + bb.y + bb.z + bb.w;
            }
#pragma unroll
            for (int off = 32; off >= 1; off >>= 1) s += __shfl_xor(s, off, 64);
            if (lane == 0) AS(&cbuf[e], s);
        }
        asm volatile("s_waitcnt vmcnt(0)" ::: "memory");
        __syncthreads();
        if (threadIdx.x == 0)
            __hip_atomic_fetch_add(bcnt, 1u, __ATOMIC_RELAXED, __HIP_MEMORY_SCOPE_AGENT);
    }

    // ====================== Phase C: token gating ======================
    {
        if (threadIdx.x == 0)
            while (AL(bcnt) < 512u) __builtin_amdgcn_s_sleep(2);
        __syncthreads();

        float cr[E_];
#pragma unroll
        for (int q = 0; q < E_; ++q) cr[q] = AL(&cbuf[q]);

        const int n0 = b * 8 + wid * 2;
        const float* x0 = x + (size_t)n0 * D_;
        const float* x1 = x0 + D_;

        float lgA[E_] = {0,0,0,0,0,0,0,0}, dvA[E_] = {0,0,0,0,0,0,0,0};
        float lgB[E_] = {0,0,0,0,0,0,0,0}, dvB[E_] = {0,0,0,0,0,0,0,0};

#pragma unroll
        for (int k = 0; k < D_ / 64; ++k) {
            int d = lane + 64 * k;
            float xa = x0[d];
            float xb = x1[d];
            const float4* wgp = (const float4*)(wg + (size_t)d * E_);
            float4 g0 = wgp[0], g1 = wgp[1];
            float v0 = AL(&vT[(size_t)d * E_ + 0]), v1 = AL(&vT[(size_t)d * E_ + 1]);
            float v2 = AL(&vT[(size_t)d * E_ + 2]), v3 = AL(&vT[(size_t)d * E_ + 3]);
            float v4 = AL(&vT[(size_t)d * E_ + 4]), v5 = AL(&vT[(size_t)d * E_ + 5]);
            float v6 = AL(&vT[(size_t)d * E_ + 6]), v7 = AL(&vT[(size_t)d * E_ + 7]);
            lgA[0] += xa * g0.x; lgA[1] += xa * g0.y; lgA[2] += xa * g0.z; lgA[3] += xa * g0.w;
            lgA[4] += xa * g1.x; lgA[5] += xa * g1.y; lgA[6] += xa * g1.z; lgA[7] += xa * g1.w;
            lgB[0] += xb * g0.x; lgB[1] += xb * g0.y; lgB[2] += xb * g0.z; lgB[3] += xb * g0.w;
            lgB[4] += xb * g1.x; lgB[5] += xb * g1.y; lgB[6] += xb * g1.z; lgB[7] += xb * g1.w;
            dvA[0] += xa * v0; dvA[1] += xa * v1; dvA[2] += xa * v2; dvA[3] += xa * v3;
            dvA[4] += xa * v4; dvA[5] += xa * v5; dvA[6] += xa * v6; dvA[7] += xa * v7;
            dvB[0] += xb * v0; dvB[1] += xb * v1; dvB[2] += xb * v2; dvB[3] += xb * v3;
            dvB[4] += xb * v4; dvB[5] += xb * v5; dvB[6] += xb * v6; dvB[7] += xb * v7;
        }

#pragma unroll
        for (int off = 32; off >= 1; off >>= 1) {
#pragma unroll
            for (int q = 0; q < E_; ++q) {
                lgA[q] += __shfl_xor(lgA[q], off, 64);
                dvA[q] += __shfl_xor(dvA[q], off, 64);
                lgB[q] += __shfl_xor(lgB[q], off, 64);
                dvB[q] += __shfl_xor(dvB[q], off, 64);
            }
        }

        if (lane == 0 || lane == 32) {
            bool isA = (lane == 0);
            float lg[E_], dvr[E_];
#pragma unroll
            for (int q = 0; q < E_; ++q) {
                lg[q]  = isA ? lgA[q] : lgB[q];
                dvr[q] = isA ? dvA[q] : dvB[q];
            }
            // top-2, tie -> lower index (jax.lax.top_k), all register
            float m0 = lg[0]; int i0 = 0;
#pragma unroll
            for (int q = 1; q < E_; ++q) if (lg[q] > m0) { m0 = lg[q]; i0 = q; }
            float m1 = -3.0e38f; int i1 = 0;
#pragma unroll
            for (int q = 0; q < E_; ++q) if (q != i0 && lg[q] > m1) { m1 = lg[q]; i1 = q; }
            float dv0 = 0.f, dv1 = 0.f, c0v = 0.f, c1v = 0.f;
#pragma unroll
            for (int q = 0; q < E_; ++q) {
                if (q == i0) { dv0 += dvr[q]; c0v += cr[q]; }
                if (q == i1) { dv1 += dvr[q]; c1v += cr[q]; }
            }
            float g1w = 1.f / (1.f + expf(m0 - m1));
            AS(&sbuf[isA ? n0 : (n0 + 1)], (1.f - g1w) * (dv0 + c0v) + g1w * (dv1 + c1v));
        }
        asm volatile("s_waitcnt vmcnt(0)" ::: "memory");
        __syncthreads();
    }

    // ====================== Phase D: last block does log-softmax ======================
    __shared__ int islast;
    if (threadIdx.x == 0) {
        unsigned old = __hip_atomic_fetch_add(ccnt, 1u, __ATOMIC_RELAXED, __HIP_MEMORY_SCOPE_AGENT);
        islast = (old == 511u) ? 1 : 0;
    }
    __syncthreads();
    if (!islast) return;

    {
        const int brow = wid;                       // 4 waves, one batch row each
        float vals[16];
        float mx = -3.0e38f;
#pragma unroll
        for (int k = 0; k < 16; ++k) {
            vals[k] = AL(&sbuf[(size_t)brow * T_ + lane + 64 * k]);
            mx = fmaxf(mx, vals[k]);
        }
#pragma unroll
        for (int off = 32; off >= 1; off >>= 1) mx = fmaxf(mx, __shfl_xor(mx, off, 64));
        float sm = 0.f;
#pragma unroll
        for (int k = 0; k < 16; ++k) sm += expf(vals[k] - mx);
#pragma unroll
        for (int off = 32; off >= 1; off >>= 1) sm += __shfl_xor(sm, off, 64);
        float lse = mx + logf(sm);
#pragma unroll
        for (int k = 0; k < 16; ++k)
            out[(size_t)brow * T_ + lane + 64 * k] = vals[k] - lse;
    }
}

// ---------------------------------------------------------------------------
extern "C" void kernel_launch(void* const* d_in, const int* in_sizes, int n_in,
                              void* d_out, int out_size, void* d_ws, size_t ws_size,
                              hipStream_t stream) {
    const float* x  = (const float*)d_in[0];   // [B, T, D]
    const float* wg = (const float*)d_in[1];   // [D, E]
    const float* w1 = (const float*)d_in[2];   // [E, D, H]
    const float* b1 = (const float*)d_in[3];   // [E, H]
    const float* w2 = (const float*)d_in[4];   // [E, H, D]
    const float* b2 = (const float*)d_in[5];   // [E, D]
    float* out = (float*)d_out;                // [B, T]

    float* ws     = (float*)d_ws;
    float* w2sum  = ws;                        // E*H = 16384 floats
    float* vT     = ws + 16384;                // D*E =  8192 floats ([D][E])
    float* cbuf   = ws + 24576;                // E
    float* sbuf   = ws + 24592;                // N = 4096
    unsigned* cnt = (unsigned*)(ws + 28688);   // ecnt[8], bcnt, ccnt

    // zero the 10 sync counters each launch (graph-capturable memset node)
    hipMemsetAsync(cnt, 0, 10 * sizeof(unsigned), stream);

    fused_kernel<<<dim3(512), dim3(256), 0, stream>>>(
        x, wg, w1, b1, w2, b2, w2sum, vT, cbuf, sbuf,
        cnt, cnt + 8, cnt + 9, out);
}

// Round 10
// 87.815 us; speedup vs baseline: 1.3121x; 1.3121x over previous
//
#include <hip/hip_runtime.h>
#include <stdint.h>

// Problem constants
#define B_ 4
#define T_ 1024
#define D_ 1024
#define H_ 2048
#define E_ 8

// Device-coherent relaxed atomics — used ONLY for small one-time data
// (w2sum handoff inside K1, sbuf handoff inside K2, counters). Bulk data
// always moves on the cached path (lesson of round 9).
#define AL(p)    __hip_atomic_load((p), __ATOMIC_RELAXED, __HIP_MEMORY_SCOPE_AGENT)
#define AS(p, v) __hip_atomic_store((p), (v), __ATOMIC_RELAXED, __HIP_MEMORY_SCOPE_AGENT)

// Fire-and-forget global->LDS staging, 16B/lane. LDS dest wave-uniform.
__device__ __forceinline__ void stage16(const float* g, float* l) {
    __builtin_amdgcn_global_load_lds(
        (const __attribute__((address_space(1))) uint32_t*)g,
        (__attribute__((address_space(3))) uint32_t*)l, 16, 0, 0);
}

// ---------------------------------------------------------------------------
// K1: phases A+B fused. 512 blocks x 256 thr, 48 KB LDS, lb(256,2) -> all
// co-resident.  A: w2sum[r]=sum_d w2[r,d] (32 rows/block, rolling 3-buf
// global_load_lds pipe).  B: vT[d*E+e]=w1[e,d,:].w2sum[e,:] (16 rows/block,
// same pipe, half-row tiles; w2sum[e] in 8 float4 regs via one-time AL).
// A->B sync: per-expert counter (64 blocks/expert) -> B overlaps A's tail.
// ---------------------------------------------------------------------------
__global__ __launch_bounds__(256, 2) void ab_kernel(
    const float* __restrict__ w1, const float* __restrict__ b1,
    const float* __restrict__ w2, const float* __restrict__ b2,
    float* __restrict__ w2sum, float* __restrict__ vT,
    float* __restrict__ cbuf, unsigned* __restrict__ ecnt)
{
    __shared__ float buf[3][4096];                 // 48 KB, 16 KB tiles
    const int b    = blockIdx.x;                   // 0..511
    const int wid  = threadIdx.x >> 6;
    const int lane = threadIdx.x & 63;
    const int e    = b >> 6;                       // expert (64 blocks/expert)

    // ====================== Phase A: w2 row sums ======================
    {
        const float* src = w2 + ((size_t)b * 32 + wid) * D_ + lane * 4;
#define ASTG(k) { const float* s_ = src + (size_t)(k) * 4 * D_;               \
                  float* d_ = &buf[(k) % 3][wid * 1024];                      \
                  stage16(s_, d_);         stage16(s_ + 256, d_ + 256);       \
                  stage16(s_ + 512, d_ + 512); stage16(s_ + 768, d_ + 768); }
        ASTG(0); ASTG(1);
        float accs[8];
#pragma unroll
        for (int k = 0; k < 8; ++k) {
            if (k < 7) asm volatile("s_waitcnt vmcnt(4)" ::: "memory");
            else       asm volatile("s_waitcnt vmcnt(0)" ::: "memory");
            if (k < 6) ASTG(k + 2);
            const float* row = &buf[k % 3][wid * 1024];
            float acc = 0.f;
#pragma unroll
            for (int j = 0; j < 4; ++j) {
                float4 a = *(const float4*)&row[j * 256 + lane * 4];
                acc += a.x + a.y + a.z + a.w;
            }
#pragma unroll
            for (int off = 32; off >= 1; off >>= 1) acc += __shfl_xor(acc, off, 64);
            accs[k] = acc;
        }
#undef ASTG
        if (lane == 0) {
#pragma unroll
            for (int k = 0; k < 8; ++k)
                AS(&w2sum[(size_t)b * 32 + k * 4 + wid], accs[k]);
        }
        asm volatile("s_waitcnt vmcnt(0)" ::: "memory");
        __syncthreads();
        if (threadIdx.x == 0)
            __hip_atomic_fetch_add(&ecnt[e], 1u, __ATOMIC_RELAXED, __HIP_MEMORY_SCOPE_AGENT);
    }

    // ====================== Phase B: v build ======================
    {
        if (threadIdx.x == 0)
            while (AL(&ecnt[e]) < 64u) __builtin_amdgcn_s_sleep(2);
        __syncthreads();

        // w2sum[e] fragment -> 8 float4 regs via one-time coherent loads
        const float* wsr = w2sum + (size_t)e * H_;
        float4 W[8];
#pragma unroll
        for (int m = 0; m < 8; ++m) {
            W[m].x = AL(wsr + m * 256 + lane * 4 + 0);
            W[m].y = AL(wsr + m * 256 + lane * 4 + 1);
            W[m].z = AL(wsr + m * 256 + lane * 4 + 2);
            W[m].w = AL(wsr + m * 256 + lane * 4 + 3);
        }
        asm volatile("s_waitcnt vmcnt(0)" ::: "memory");   // vmcnt clean

        const int d0 = (b & 63) * 16;
        const float* bsrc = w1 + ((size_t)e * D_ + d0 + wid) * H_ + lane * 4;
        // tile t = (rg = t>>1, half h = t&1): 4KB/wave slice of row d0+rg*4+wid
#define BSTG(t) { const float* s_ = bsrc + (size_t)((t) >> 1) * 4 * H_ + ((t) & 1) * 1024; \
                  float* d_ = &buf[(t) % 3][wid * 1024];                      \
                  stage16(s_, d_);         stage16(s_ + 256, d_ + 256);       \
                  stage16(s_ + 512, d_ + 512); stage16(s_ + 768, d_ + 768); }
        BSTG(0); BSTG(1);
        float bacc[4] = {0.f, 0.f, 0.f, 0.f};
#pragma unroll
        for (int t = 0; t < 8; ++t) {
            if (t < 7) asm volatile("s_waitcnt vmcnt(4)" ::: "memory");
            else       asm volatile("s_waitcnt vmcnt(0)" ::: "memory");
            if (t < 6) BSTG(t + 2);
            const float* row = &buf[t % 3][wid * 1024];
            const int h4 = (t & 1) * 4;
            float a = 0.f;
#pragma unroll
            for (int j = 0; j < 4; ++j) {
                float4 av = *(const float4*)&row[j * 256 + lane * 4];
                float4 wv = W[h4 + j];
                a += av.x * wv.x + av.y * wv.y + av.z * wv.z + av.w * wv.w;
            }
            bacc[t >> 1] += a;
        }
#undef BSTG
#pragma unroll
        for (int rg = 0; rg < 4; ++rg) {
#pragma unroll
            for (int off = 32; off >= 1; off >>= 1)
                bacc[rg] += __shfl_xor(bacc[rg], off, 64);
        }
        if (lane == 0) {
#pragma unroll
            for (int rg = 0; rg < 4; ++rg)
                vT[(size_t)(d0 + rg * 4 + wid) * E_ + e] = bacc[rg];  // cached; K2 boundary flushes
        }

        // c[e] = b1[e,:].w2sum[e,:] + sum_d b2[e,d]  (W regs still live)
        if ((b & 63) == 0 && wid == 0) {
            const float4* bp = (const float4*)(b1 + (size_t)e * H_) + lane;
            float s = 0.f;
#pragma unroll
            for (int m = 0; m < 8; ++m) {
                float4 q = bp[m * 64];
                float4 wv = W[m];
                s += q.x * wv.x + q.y * wv.y + q.z * wv.z + q.w * wv.w;
            }
            const float4* cp = (const float4*)(b2 + (size_t)e * D_) + lane;
#pragma unroll
            for (int j = 0; j < 4; ++j) {
                float4 bb = cp[j * 64];
                s += bb.x + bb.y + bb.z + bb.w;
            }
#pragma unroll
            for (int off = 32; off >= 1; off >>= 1) s += __shfl_xor(s, off, 64);
            if (lane == 0) cbuf[e] = s;
        }
    }
}

// ---------------------------------------------------------------------------
// K2: phases C+D fused. 1024 blocks x 256 thr, one token per wave.
// C: logits[e]=x[n,:].wg[:,e], dv[e]=x[n,:].vT[:,e] (cached float4 loads;
//    x vectorized float4), top-2 (tie->lower idx), s[n]=sum g*(dv+c).
// D: last block (ccnt) recomputes log-softmax from sbuf via AL (16 KB).
// ---------------------------------------------------------------------------
__global__ __launch_bounds__(256) void cd_kernel(
    const float* __restrict__ x,  const float* __restrict__ wg,
    const float* __restrict__ vT, const float* __restrict__ cbuf,
    float* __restrict__ sbuf, unsigned* __restrict__ ccnt,
    float* __restrict__ out)
{
    const int wid  = threadIdx.x >> 6;
    const int lane = threadIdx.x & 63;
    const int n    = blockIdx.x * 4 + wid;
    const float* xr = x + (size_t)n * D_;

    float lg[E_] = {0,0,0,0,0,0,0,0};
    float dv[E_] = {0,0,0,0,0,0,0,0};

#pragma unroll
    for (int it = 0; it < 4; ++it) {                    // 256 d per iter
        const int dbase = it * 256 + lane * 4;
        float4 xv = *(const float4*)&xr[dbase];
#pragma unroll
        for (int dd = 0; dd < 4; ++dd) {
            float xs = (dd == 0) ? xv.x : (dd == 1) ? xv.y : (dd == 2) ? xv.z : xv.w;
            const float4* wgp = (const float4*)(wg + (size_t)(dbase + dd) * E_);
            const float4* vp  = (const float4*)(vT + (size_t)(dbase + dd) * E_);
            float4 g0 = wgp[0], g1 = wgp[1];
            float4 v0 = vp[0],  v1 = vp[1];
            lg[0] += xs * g0.x; lg[1] += xs * g0.y; lg[2] += xs * g0.z; lg[3] += xs * g0.w;
            lg[4] += xs * g1.x; lg[5] += xs * g1.y; lg[6] += xs * g1.z; lg[7] += xs * g1.w;
            dv[0] += xs * v0.x; dv[1] += xs * v0.y; dv[2] += xs * v0.z; dv[3] += xs * v0.w;
            dv[4] += xs * v1.x; dv[5] += xs * v1.y; dv[6] += xs * v1.z; dv[7] += xs * v1.w;
        }
    }

#pragma unroll
    for (int off = 32; off >= 1; off >>= 1) {
#pragma unroll
        for (int q = 0; q < E_; ++q) {
            lg[q] += __shfl_xor(lg[q], off, 64);
            dv[q] += __shfl_xor(dv[q], off, 64);
        }
    }

    if (lane == 0) {
        // top-2, tie -> lower index (jax.lax.top_k semantics)
        float m0 = lg[0]; int i0 = 0;
#pragma unroll
        for (int q = 1; q < E_; ++q) if (lg[q] > m0) { m0 = lg[q]; i0 = q; }
        float m1 = -3.0e38f; int i1 = 0;
#pragma unroll
        for (int q = 0; q < E_; ++q) if (q != i0 && lg[q] > m1) { m1 = lg[q]; i1 = q; }
        float dv0 = 0.f, dv1 = 0.f, c0v = 0.f, c1v = 0.f;
#pragma unroll
        for (int q = 0; q < E_; ++q) {
            if (q == i0) { dv0 += dv[q]; c0v += cbuf[q]; }
            if (q == i1) { dv1 += dv[q]; c1v += cbuf[q]; }
        }
        float g1w = 1.f / (1.f + expf(m0 - m1));
        AS(&sbuf[n], (1.f - g1w) * (dv0 + c0v) + g1w * (dv1 + c1v));
    }

    // last-block handoff (no threadfence; AS/AL relaxed path only)
    asm volatile("s_waitcnt vmcnt(0)" ::: "memory");
    __syncthreads();
    __shared__ int islast;
    if (threadIdx.x == 0) {
        unsigned old = __hip_atomic_fetch_add(ccnt, 1u, __ATOMIC_RELAXED, __HIP_MEMORY_SCOPE_AGENT);
        islast = (old == (unsigned)(gridDim.x - 1)) ? 1 : 0;
    }
    __syncthreads();
    if (!islast) return;

    {   // Phase D: 4 waves, one batch row each
        const int brow = wid;
        float vals[16];
        float mx = -3.0e38f;
#pragma unroll
        for (int k = 0; k < 16; ++k) {
            vals[k] = AL(&sbuf[(size_t)brow * T_ + lane + 64 * k]);
            mx = fmaxf(mx, vals[k]);
        }
#pragma unroll
        for (int off = 32; off >= 1; off >>= 1) mx = fmaxf(mx, __shfl_xor(mx, off, 64));
        float sm = 0.f;
#pragma unroll
        for (int k = 0; k < 16; ++k) sm += expf(vals[k] - mx);
#pragma unroll
        for (int off = 32; off >= 1; off >>= 1) sm += __shfl_xor(sm, off, 64);
        float lse = mx + logf(sm);
#pragma unroll
        for (int k = 0; k < 16; ++k)
            out[(size_t)brow * T_ + lane + 64 * k] = vals[k] - lse;
    }
}

// ---------------------------------------------------------------------------
extern "C" void kernel_launch(void* const* d_in, const int* in_sizes, int n_in,
                              void* d_out, int out_size, void* d_ws, size_t ws_size,
                              hipStream_t stream) {
    const float* x  = (const float*)d_in[0];   // [B, T, D]
    const float* wg = (const float*)d_in[1];   // [D, E]
    const float* w1 = (const float*)d_in[2];   // [E, D, H]
    const float* b1 = (const float*)d_in[3];   // [E, H]
    const float* w2 = (const float*)d_in[4];   // [E, H, D]
    const float* b2 = (const float*)d_in[5];   // [E, D]
    float* out = (float*)d_out;                // [B, T]

    float* ws     = (float*)d_ws;
    float* w2sum  = ws;                        // E*H = 16384 floats
    float* vT     = ws + 16384;                // D*E =  8192 floats ([D][E])
    float* cbuf   = ws + 24576;                // E
    float* sbuf   = ws + 24592;                // N = 4096
    unsigned* cnt = (unsigned*)(ws + 28688);   // ecnt[8], ccnt

    // zero sync counters each launch (graph-capturable memset node)
    hipMemsetAsync(cnt, 0, 10 * sizeof(unsigned), stream);

    // K1: A+B fused (512 blocks, co-resident, per-expert spin)
    ab_kernel<<<dim3(512), dim3(256), 0, stream>>>(
        w1, b1, w2, b2, w2sum, vT, cbuf, cnt);
    // K2: C+D fused (1024 blocks; last block does log-softmax)
    cd_kernel<<<dim3(1024), dim3(256), 0, stream>>>(
        x, wg, vT, cbuf, sbuf, cnt + 8, out);
}

// Round 11
// 58.525 us; speedup vs baseline: 1.9687x; 1.5005x over previous
//
#include <hip/hip_runtime.h>
#include <stdint.h>

// Problem constants
#define B_ 4
#define T_ 1024
#define D_ 1024
#define H_ 2048
#define E_ 8

// Device-coherent relaxed atomics — ONLY for tiny cross-block data inside
// one kernel (sbuf handoff to the last block, counter). Bulk data always
// travels cached across kernel boundaries (lessons of rounds 9/10).
#define AL(p)    __hip_atomic_load((p), __ATOMIC_RELAXED, __HIP_MEMORY_SCOPE_AGENT)
#define AS(p, v) __hip_atomic_store((p), (v), __ATOMIC_RELAXED, __HIP_MEMORY_SCOPE_AGENT)

// Fire-and-forget global->LDS staging, 16B/lane. LDS dest wave-uniform.
__device__ __forceinline__ void stage16(const float* g, float* l) {
    __builtin_amdgcn_global_load_lds(
        (const __attribute__((address_space(1))) uint32_t*)g,
        (__attribute__((address_space(3))) uint32_t*)l, 16, 0, 0);
}

// Batched device-coherent 16B loads (4 at once, one drain) — for the last
// block's sbuf read in CD. sc0 sc1 -> read at device coherence point.
__device__ __forceinline__ void load4x16_sc(const float* p0, const float* p1,
                                            const float* p2, const float* p3,
                                            float4& r0, float4& r1,
                                            float4& r2, float4& r3) {
    asm volatile(
        "global_load_dwordx4 %0, %4, off sc0 sc1\n\t"
        "global_load_dwordx4 %1, %5, off sc0 sc1\n\t"
        "global_load_dwordx4 %2, %6, off sc0 sc1\n\t"
        "global_load_dwordx4 %3, %7, off sc0 sc1\n\t"
        "s_waitcnt vmcnt(0)"
        : "=&v"(r0), "=&v"(r1), "=&v"(r2), "=&v"(r3)
        : "v"(p0), "v"(p1), "v"(p2), "v"(p3)
        : "memory");
}

// --------------------------------------------------------------------------
// Kernel A: w2sum[r] = sum_d w2_flat[r, d] (row = D = 1024 floats).
// 512 blocks x 256 thr; block = 32 rows = 8 tiles of 4 rows, triple-buffered
// rolling global_load_lds pipeline, wave-private (no barriers). Shfl-reduce
// trees DEFERRED out of the vmcnt-gated loop (8 independent trees pipeline).
// --------------------------------------------------------------------------
__global__ __launch_bounds__(256) void w2sum_kernel(const float* __restrict__ w2,
                                                    float* __restrict__ w2sum) {
    __shared__ float buf[3][4096];                 // 48 KB
    const int wid = threadIdx.x >> 6, lane = threadIdx.x & 63;
    const float* src = w2 + ((size_t)blockIdx.x * 32 + wid) * D_ + lane * 4;

#define ASTG(k) { const float* s_ = src + (size_t)(k) * 4 * D_;               \
                  float* d_ = &buf[(k) % 3][wid * 1024];                      \
                  stage16(s_, d_);         stage16(s_ + 256, d_ + 256);       \
                  stage16(s_ + 512, d_ + 512); stage16(s_ + 768, d_ + 768); }
    ASTG(0); ASTG(1);
    float accs[8];
#pragma unroll
    for (int k = 0; k < 8; ++k) {
        if (k < 7) asm volatile("s_waitcnt vmcnt(4)" ::: "memory");
        else       asm volatile("s_waitcnt vmcnt(0)" ::: "memory");
        if (k < 6) ASTG(k + 2);
        const float* row = &buf[k % 3][wid * 1024];
        float4 a0 = *(const float4*)&row[0 * 256 + lane * 4];
        float4 a1 = *(const float4*)&row[1 * 256 + lane * 4];
        float4 a2 = *(const float4*)&row[2 * 256 + lane * 4];
        float4 a3 = *(const float4*)&row[3 * 256 + lane * 4];
        accs[k] = (a0.x + a0.y + a0.z + a0.w) + (a1.x + a1.y + a1.z + a1.w)
                + (a2.x + a2.y + a2.z + a2.w) + (a3.x + a3.y + a3.z + a3.w);
    }
#undef ASTG
    // deferred independent reduce trees
#pragma unroll
    for (int off = 32; off >= 1; off >>= 1) {
#pragma unroll
        for (int k = 0; k < 8; ++k) accs[k] += __shfl_xor(accs[k], off, 64);
    }
    if (lane == 0) {
        const int r0 = blockIdx.x * 32 + wid;
#pragma unroll
        for (int k = 0; k < 8; ++k) w2sum[r0 + k * 4] = accs[k];  // cached
    }
}

// --------------------------------------------------------------------------
// Kernel B: vT[d*E + e] = dot(w1[e,d,:], w2sum[e,:]).  (round-8 champion)
// 512 blocks x 256 thr; block = expert bid>>6, rows d0=(bid&63)*16 as
// 4 tiles of 4 rows, double-buffered (64 KB). w2sum[e] fragment in 8 float4
// regs (cached loads; A->B kernel boundary provides coherence). Wave-private
// rolling pipeline, counted vmcnt. c[e] from regs by expert's first block.
// --------------------------------------------------------------------------
__global__ __launch_bounds__(256) void v_build_kernel(const float* __restrict__ w1,
                                                      const float* __restrict__ w2sum,
                                                      const float* __restrict__ b1,
                                                      const float* __restrict__ b2,
                                                      float* __restrict__ vT,
                                                      float* __restrict__ c) {
    __shared__ float buf[2][4 * H_];                   // 64 KB
    const int bid = blockIdx.x;
    const int e   = bid >> 6;                          // 64 blocks/expert
    const int d0  = (bid & 63) * 16;
    const int wid = threadIdx.x >> 6, lane = threadIdx.x & 63;
    const float* src = w1 + ((size_t)e * D_ + d0 + wid) * H_ + lane * 4;

    const float4* wsp = (const float4*)(w2sum + (size_t)e * H_) + lane;
    float4 s0 = wsp[0],   s1 = wsp[64],  s2 = wsp[128], s3 = wsp[192],
           s4 = wsp[256], s5 = wsp[320], s6 = wsp[384], s7 = wsp[448];
    asm volatile("" ::: "memory");

#define BSTG(k)                                                            \
    {                                                                      \
        const float* s_ = src + (size_t)(k) * 4 * H_;                      \
        float* d_ = &buf[(k) & 1][wid * H_];                               \
        stage16(s_,        d_);        stage16(s_ + 256,  d_ + 256);       \
        stage16(s_ + 512,  d_ + 512);  stage16(s_ + 768,  d_ + 768);       \
        stage16(s_ + 1024, d_ + 1024); stage16(s_ + 1280, d_ + 1280);      \
        stage16(s_ + 1536, d_ + 1536); stage16(s_ + 1792, d_ + 1792);      \
    }

    BSTG(0); BSTG(1);
    float accs[4];
#pragma unroll
    for (int k = 0; k < 4; ++k) {
        if (k < 3) asm volatile("s_waitcnt vmcnt(8)" ::: "memory");
        else       asm volatile("s_waitcnt vmcnt(0)" ::: "memory");
        const float* row = &buf[k & 1][wid * H_];
        float acc;
        {
            float4 a0 = *(const float4*)&row[0 * 256 + lane * 4];
            float4 a1 = *(const float4*)&row[1 * 256 + lane * 4];
            float4 a2 = *(const float4*)&row[2 * 256 + lane * 4];
            float4 a3 = *(const float4*)&row[3 * 256 + lane * 4];
            float4 a4 = *(const float4*)&row[4 * 256 + lane * 4];
            float4 a5 = *(const float4*)&row[5 * 256 + lane * 4];
            float4 a6 = *(const float4*)&row[6 * 256 + lane * 4];
            float4 a7 = *(const float4*)&row[7 * 256 + lane * 4];
            acc = a0.x*s0.x + a0.y*s0.y + a0.z*s0.z + a0.w*s0.w
                + a1.x*s1.x + a1.y*s1.y + a1.z*s1.z + a1.w*s1.w
                + a2.x*s2.x + a2.y*s2.y + a2.z*s2.z + a2.w*s2.w
                + a3.x*s3.x + a3.y*s3.y + a3.z*s3.z + a3.w*s3.w
                + a4.x*s4.x + a4.y*s4.y + a4.z*s4.z + a4.w*s4.w
                + a5.x*s5.x + a5.y*s5.y + a5.z*s5.z + a5.w*s5.w
                + a6.x*s6.x + a6.y*s6.y + a6.z*s6.z + a6.w*s6.w
                + a7.x*s7.x + a7.y*s7.y + a7.z*s7.z + a7.w*s7.w;
        }
        accs[k] = acc;
        if (k < 2) BSTG(k + 2);
    }
#undef BSTG
#pragma unroll
    for (int off = 32; off >= 1; off >>= 1) {
#pragma unroll
        for (int k = 0; k < 4; ++k) accs[k] += __shfl_xor(accs[k], off, 64);
    }
    if (lane == 0) {
#pragma unroll
        for (int k = 0; k < 4; ++k)
            vT[(size_t)(d0 + k * 4 + wid) * E_ + e] = accs[k];  // cached
    }

    // c[e] = b1[e,:].w2sum[e,:] + sum_d b2[e,d]   (ws regs still live)
    if ((bid & 63) == 0 && wid == 0) {
        const float4* bp = (const float4*)(b1 + (size_t)e * H_) + lane;
        float4 q0 = bp[0],   q1 = bp[64],  q2 = bp[128], q3 = bp[192],
               q4 = bp[256], q5 = bp[320], q6 = bp[384], q7 = bp[448];
        float s = q0.x*s0.x + q0.y*s0.y + q0.z*s0.z + q0.w*s0.w
                + q1.x*s1.x + q1.y*s1.y + q1.z*s1.z + q1.w*s1.w
                + q2.x*s2.x + q2.y*s2.y + q2.z*s2.z + q2.w*s2.w
                + q3.x*s3.x + q3.y*s3.y + q3.z*s3.z + q3.w*s3.w
                + q4.x*s4.x + q4.y*s4.y + q4.z*s4.z + q4.w*s4.w
                + q5.x*s5.x + q5.y*s5.y + q5.z*s5.z + q5.w*s5.w
                + q6.x*s6.x + q6.y*s6.y + q6.z*s6.z + q6.w*s6.w
                + q7.x*s7.x + q7.y*s7.y + q7.z*s7.z + q7.w*s7.w;
        const float4* cp = (const float4*)(b2 + (size_t)e * D_) + lane;
#pragma unroll
        for (int j = 0; j < 4; ++j) {
            float4 bb = cp[j * 64];
            s += bb.x + bb.y + bb.z + bb.w;
        }
#pragma unroll
        for (int off = 32; off >= 1; off >>= 1) s += __shfl_xor(s, off, 64);
        if (lane == 0) c[e] = s;
    }
}

// --------------------------------------------------------------------------
// Kernel CD: gating + collapsed expert sum (2 tokens/wave, float4 x-loads),
// then the LAST block (counter) computes the per-batch-row log-softmax.
// wg/vT/x/cbuf read CACHED (B->CD boundary flushes); sbuf crosses blocks
// within this kernel -> sc stores + batched sc16 loads (16 KB, ~1 us).
// 512 blocks x 256 thr.
// --------------------------------------------------------------------------
__global__ __launch_bounds__(256) void cd_kernel(
    const float* __restrict__ x,  const float* __restrict__ wg,
    const float* __restrict__ vT, const float* __restrict__ cbuf,
    float* __restrict__ sbuf, unsigned* __restrict__ ccnt,
    float* __restrict__ out)
{
    const int wid  = threadIdx.x >> 6;
    const int lane = threadIdx.x & 63;
    const int n0   = (blockIdx.x * 4 + wid) * 2;
    const float* x0 = x + (size_t)n0 * D_;
    const float* x1 = x0 + D_;

    float lgA[E_] = {0,0,0,0,0,0,0,0}, dvA[E_] = {0,0,0,0,0,0,0,0};
    float lgB[E_] = {0,0,0,0,0,0,0,0}, dvB[E_] = {0,0,0,0,0,0,0,0};

#pragma unroll
    for (int it = 0; it < 4; ++it) {                    // 256 d per iter
        const int dbase = it * 256 + lane * 4;
        float4 xa4 = *(const float4*)&x0[dbase];
        float4 xb4 = *(const float4*)&x1[dbase];
#pragma unroll
        for (int dd = 0; dd < 4; ++dd) {
            float xa = (dd == 0) ? xa4.x : (dd == 1) ? xa4.y : (dd == 2) ? xa4.z : xa4.w;
            float xb = (dd == 0) ? xb4.x : (dd == 1) ? xb4.y : (dd == 2) ? xb4.z : xb4.w;
            const float4* wgp = (const float4*)(wg + (size_t)(dbase + dd) * E_);
            const float4* vp  = (const float4*)(vT + (size_t)(dbase + dd) * E_);
            float4 g0 = wgp[0], g1 = wgp[1];
            float4 v0 = vp[0],  v1 = vp[1];
            lgA[0] += xa * g0.x; lgA[1] += xa * g0.y; lgA[2] += xa * g0.z; lgA[3] += xa * g0.w;
            lgA[4] += xa * g1.x; lgA[5] += xa * g1.y; lgA[6] += xa * g1.z; lgA[7] += xa * g1.w;
            dvA[0] += xa * v0.x; dvA[1] += xa * v0.y; dvA[2] += xa * v0.z; dvA[3] += xa * v0.w;
            dvA[4] += xa * v1.x; dvA[5] += xa * v1.y; dvA[6] += xa * v1.z; dvA[7] += xa * v1.w;
            lgB[0] += xb * g0.x; lgB[1] += xb * g0.y; lgB[2] += xb * g0.z; lgB[3] += xb * g0.w;
            lgB[4] += xb * g1.x; lgB[5] += xb * g1.y; lgB[6] += xb * g1.z; lgB[7] += xb * g1.w;
            dvB[0] += xb * v0.x; dvB[1] += xb * v0.y; dvB[2] += xb * v0.z; dvB[3] += xb * v0.w;
            dvB[4] += xb * v1.x; dvB[5] += xb * v1.y; dvB[6] += xb * v1.z; dvB[7] += xb * v1.w;
        }
    }

#pragma unroll
    for (int off = 32; off >= 1; off >>= 1) {
#pragma unroll
        for (int q = 0; q < E_; ++q) {
            lgA[q] += __shfl_xor(lgA[q], off, 64);
            dvA[q] += __shfl_xor(dvA[q], off, 64);
            lgB[q] += __shfl_xor(lgB[q], off, 64);
            dvB[q] += __shfl_xor(dvB[q], off, 64);
        }
    }

    if (lane == 0 || lane == 32) {
        const bool isA = (lane == 0);
        float lg[E_], dvr[E_];
#pragma unroll
        for (int q = 0; q < E_; ++q) {
            lg[q]  = isA ? lgA[q] : lgB[q];
            dvr[q] = isA ? dvA[q] : dvB[q];
        }
        // top-2, tie -> lower index (jax.lax.top_k semantics)
        float m0 = lg[0]; int i0 = 0;
#pragma unroll
        for (int q = 1; q < E_; ++q) if (lg[q] > m0) { m0 = lg[q]; i0 = q; }
        float m1 = -3.0e38f; int i1 = 0;
#pragma unroll
        for (int q = 0; q < E_; ++q) if (q != i0 && lg[q] > m1) { m1 = lg[q]; i1 = q; }
        float dv0 = 0.f, dv1 = 0.f, c0v = 0.f, c1v = 0.f;
#pragma unroll
        for (int q = 0; q < E_; ++q) {
            if (q == i0) { dv0 += dvr[q]; c0v += cbuf[q]; }
            if (q == i1) { dv1 += dvr[q]; c1v += cbuf[q]; }
        }
        float g1w = 1.f / (1.f + expf(m0 - m1));
        AS(&sbuf[isA ? n0 : (n0 + 1)], (1.f - g1w) * (dv0 + c0v) + g1w * (dv1 + c1v));
    }

    // last-block handoff
    asm volatile("s_waitcnt vmcnt(0)" ::: "memory");
    __syncthreads();
    __shared__ int islast;
    if (threadIdx.x == 0) {
        unsigned old = __hip_atomic_fetch_add(ccnt, 1u, __ATOMIC_RELAXED, __HIP_MEMORY_SCOPE_AGENT);
        islast = (old == (unsigned)(gridDim.x - 1)) ? 1 : 0;
    }
    __syncthreads();
    if (!islast) return;

    {   // Phase D: 4 waves, one batch row each; batched sc16 sbuf reads
        const int brow = wid;
        const float* row = sbuf + (size_t)brow * T_;
        float4 v0, v1, v2, v3;
        load4x16_sc(row + lane * 4 + 0 * 256, row + lane * 4 + 1 * 256,
                    row + lane * 4 + 2 * 256, row + lane * 4 + 3 * 256,
                    v0, v1, v2, v3);
        float vals[16] = {v0.x, v0.y, v0.z, v0.w, v1.x, v1.y, v1.z, v1.w,
                          v2.x, v2.y, v2.z, v2.w, v3.x, v3.y, v3.z, v3.w};
        float mx = -3.0e38f;
#pragma unroll
        for (int k = 0; k < 16; ++k) mx = fmaxf(mx, vals[k]);
#pragma unroll
        for (int off = 32; off >= 1; off >>= 1) mx = fmaxf(mx, __shfl_xor(mx, off, 64));
        float sm = 0.f;
#pragma unroll
        for (int k = 0; k < 16; ++k) sm += expf(vals[k] - mx);
#pragma unroll
        for (int off = 32; off >= 1; off >>= 1) sm += __shfl_xor(sm, off, 64);
        float lse = mx + logf(sm);
        // vals[k] order: k = j*4+c maps to t = lane*4 + j*256 + c
#pragma unroll
        for (int j = 0; j < 4; ++j) {
            float4 o;
            o.x = vals[j * 4 + 0] - lse; o.y = vals[j * 4 + 1] - lse;
            o.z = vals[j * 4 + 2] - lse; o.w = vals[j * 4 + 3] - lse;
            *(float4*)&out[(size_t)brow * T_ + lane * 4 + j * 256] = o;
        }
    }
}

// ---------------------------------------------------------------------------
extern "C" void kernel_launch(void* const* d_in, const int* in_sizes, int n_in,
                              void* d_out, int out_size, void* d_ws, size_t ws_size,
                              hipStream_t stream) {
    const float* x  = (const float*)d_in[0];   // [B, T, D]
    const float* wg = (const float*)d_in[1];   // [D, E]
    const float* w1 = (const float*)d_in[2];   // [E, D, H]
    const float* b1 = (const float*)d_in[3];   // [E, H]
    const float* w2 = (const float*)d_in[4];   // [E, H, D]
    const float* b2 = (const float*)d_in[5];   // [E, D]
    float* out = (float*)d_out;                // [B, T]

    float* ws     = (float*)d_ws;
    float* w2sum  = ws;                        // E*H = 16384 floats
    float* vT     = ws + 16384;                // D*E =  8192 floats ([D][E])
    float* cbuf   = ws + 24576;                // E
    float* sbuf   = ws + 24592;                // N = 4096
    unsigned* cnt = (unsigned*)(ws + 28688);   // ccnt

    // zero the CD completion counter (4 B memset node, graph-capturable)
    hipMemsetAsync(cnt, 0, sizeof(unsigned), stream);

    // A: 16384 rows, 32 rows/block (8-tile rolling pipeline) -> 512 blocks
    w2sum_kernel<<<dim3(512), dim3(256), 0, stream>>>(w2, w2sum);
    // B: 8192 rows, 16 rows/block (4-tile rolling pipeline) -> 512 blocks
    v_build_kernel<<<dim3(512), dim3(256), 0, stream>>>(w1, w2sum, b1, b2, vT, cbuf);
    // CD: 4096 tokens, 2/wave -> 512 blocks; last block does log-softmax
    cd_kernel<<<dim3(512), dim3(256), 0, stream>>>(x, wg, vT, cbuf, sbuf, cnt, out);
}

// Round 12
// 50.584 us; speedup vs baseline: 2.2777x; 1.1570x over previous
//
#include <hip/hip_runtime.h>
#include <stdint.h>

// Problem constants
#define B_ 4
#define T_ 1024
#define D_ 1024
#define H_ 2048
#define E_ 8

// Device-coherent relaxed atomics — ONLY for tiny cross-block data inside
// one kernel (sbuf handoff to the last block, counter). Bulk data always
// travels cached across kernel boundaries (lessons of rounds 9/10).
#define AL(p)    __hip_atomic_load((p), __ATOMIC_RELAXED, __HIP_MEMORY_SCOPE_AGENT)
#define AS(p, v) __hip_atomic_store((p), (v), __ATOMIC_RELAXED, __HIP_MEMORY_SCOPE_AGENT)

// Fire-and-forget global->LDS staging, 16B/lane. LDS dest wave-uniform.
__device__ __forceinline__ void stage16(const float* g, float* l) {
    __builtin_amdgcn_global_load_lds(
        (const __attribute__((address_space(1))) uint32_t*)g,
        (__attribute__((address_space(3))) uint32_t*)l, 16, 0, 0);
}

// Batched device-coherent 16B loads (4 at once, one drain) — for the last
// block's sbuf read in CD. sc0 sc1 -> read at device coherence point.
__device__ __forceinline__ void load4x16_sc(const float* p0, const float* p1,
                                            const float* p2, const float* p3,
                                            float4& r0, float4& r1,
                                            float4& r2, float4& r3) {
    asm volatile(
        "global_load_dwordx4 %0, %4, off sc0 sc1\n\t"
        "global_load_dwordx4 %1, %5, off sc0 sc1\n\t"
        "global_load_dwordx4 %2, %6, off sc0 sc1\n\t"
        "global_load_dwordx4 %3, %7, off sc0 sc1\n\t"
        "s_waitcnt vmcnt(0)"
        : "=&v"(r0), "=&v"(r1), "=&v"(r2), "=&v"(r3)
        : "v"(p0), "v"(p1), "v"(p2), "v"(p3)
        : "memory");
}

// --------------------------------------------------------------------------
// Kernel A: w2sum[r] = sum_d w2_flat[r, d] (row = D = 1024 floats).
// 512 blocks x 256 thr; block = 32 rows = 8 tiles of 4 rows, triple-buffered
// rolling global_load_lds pipeline, wave-private (no barriers). Shfl-reduce
// trees deferred out of the vmcnt-gated loop.
// --------------------------------------------------------------------------
__global__ __launch_bounds__(256) void w2sum_kernel(const float* __restrict__ w2,
                                                    float* __restrict__ w2sum) {
    __shared__ float buf[3][4096];                 // 48 KB
    const int wid = threadIdx.x >> 6, lane = threadIdx.x & 63;
    const float* src = w2 + ((size_t)blockIdx.x * 32 + wid) * D_ + lane * 4;

#define ASTG(k) { const float* s_ = src + (size_t)(k) * 4 * D_;               \
                  float* d_ = &buf[(k) % 3][wid * 1024];                      \
                  stage16(s_, d_);         stage16(s_ + 256, d_ + 256);       \
                  stage16(s_ + 512, d_ + 512); stage16(s_ + 768, d_ + 768); }
    ASTG(0); ASTG(1);
    float accs[8];
#pragma unroll
    for (int k = 0; k < 8; ++k) {
        if (k < 7) asm volatile("s_waitcnt vmcnt(4)" ::: "memory");
        else       asm volatile("s_waitcnt vmcnt(0)" ::: "memory");
        if (k < 6) ASTG(k + 2);
        const float* row = &buf[k % 3][wid * 1024];
        float4 a0 = *(const float4*)&row[0 * 256 + lane * 4];
        float4 a1 = *(const float4*)&row[1 * 256 + lane * 4];
        float4 a2 = *(const float4*)&row[2 * 256 + lane * 4];
        float4 a3 = *(const float4*)&row[3 * 256 + lane * 4];
        accs[k] = (a0.x + a0.y + a0.z + a0.w) + (a1.x + a1.y + a1.z + a1.w)
                + (a2.x + a2.y + a2.z + a2.w) + (a3.x + a3.y + a3.z + a3.w);
    }
#undef ASTG
#pragma unroll
    for (int off = 32; off >= 1; off >>= 1) {
#pragma unroll
        for (int k = 0; k < 8; ++k) accs[k] += __shfl_xor(accs[k], off, 64);
    }
    if (lane == 0) {
        const int r0 = blockIdx.x * 32 + wid;
#pragma unroll
        for (int k = 0; k < 8; ++k) w2sum[r0 + k * 4] = accs[k];  // cached
    }
}

// --------------------------------------------------------------------------
// Kernel B: vT[d*E + e] = dot(w1[e,d,:], w2sum[e,:]).  (round-8 champion)
// 512 blocks x 256 thr; block = expert bid>>6, rows d0=(bid&63)*16 as
// 4 tiles of 4 rows, double-buffered (64 KB). w2sum[e] fragment in 8 float4
// regs (cached; A->B kernel boundary provides coherence). Wave-private
// rolling pipeline, counted vmcnt. c[e] from regs by expert's first block.
// --------------------------------------------------------------------------
__global__ __launch_bounds__(256) void v_build_kernel(const float* __restrict__ w1,
                                                      const float* __restrict__ w2sum,
                                                      const float* __restrict__ b1,
                                                      const float* __restrict__ b2,
                                                      float* __restrict__ vT,
                                                      float* __restrict__ c) {
    __shared__ float buf[2][4 * H_];                   // 64 KB
    const int bid = blockIdx.x;
    const int e   = bid >> 6;                          // 64 blocks/expert
    const int d0  = (bid & 63) * 16;
    const int wid = threadIdx.x >> 6, lane = threadIdx.x & 63;
    const float* src = w1 + ((size_t)e * D_ + d0 + wid) * H_ + lane * 4;

    const float4* wsp = (const float4*)(w2sum + (size_t)e * H_) + lane;
    float4 s0 = wsp[0],   s1 = wsp[64],  s2 = wsp[128], s3 = wsp[192],
           s4 = wsp[256], s5 = wsp[320], s6 = wsp[384], s7 = wsp[448];
    asm volatile("" ::: "memory");

#define BSTG(k)                                                            \
    {                                                                      \
        const float* s_ = src + (size_t)(k) * 4 * H_;                      \
        float* d_ = &buf[(k) & 1][wid * H_];                               \
        stage16(s_,        d_);        stage16(s_ + 256,  d_ + 256);       \
        stage16(s_ + 512,  d_ + 512);  stage16(s_ + 768,  d_ + 768);       \
        stage16(s_ + 1024, d_ + 1024); stage16(s_ + 1280, d_ + 1280);      \
        stage16(s_ + 1536, d_ + 1536); stage16(s_ + 1792, d_ + 1792);      \
    }

    BSTG(0); BSTG(1);
    float accs[4];
#pragma unroll
    for (int k = 0; k < 4; ++k) {
        if (k < 3) asm volatile("s_waitcnt vmcnt(8)" ::: "memory");
        else       asm volatile("s_waitcnt vmcnt(0)" ::: "memory");
        const float* row = &buf[k & 1][wid * H_];
        float acc;
        {
            float4 a0 = *(const float4*)&row[0 * 256 + lane * 4];
            float4 a1 = *(const float4*)&row[1 * 256 + lane * 4];
            float4 a2 = *(const float4*)&row[2 * 256 + lane * 4];
            float4 a3 = *(const float4*)&row[3 * 256 + lane * 4];
            float4 a4 = *(const float4*)&row[4 * 256 + lane * 4];
            float4 a5 = *(const float4*)&row[5 * 256 + lane * 4];
            float4 a6 = *(const float4*)&row[6 * 256 + lane * 4];
            float4 a7 = *(const float4*)&row[7 * 256 + lane * 4];
            acc = a0.x*s0.x + a0.y*s0.y + a0.z*s0.z + a0.w*s0.w
                + a1.x*s1.x + a1.y*s1.y + a1.z*s1.z + a1.w*s1.w
                + a2.x*s2.x + a2.y*s2.y + a2.z*s2.z + a2.w*s2.w
                + a3.x*s3.x + a3.y*s3.y + a3.z*s3.z + a3.w*s3.w
                + a4.x*s4.x + a4.y*s4.y + a4.z*s4.z + a4.w*s4.w
                + a5.x*s5.x + a5.y*s5.y + a5.z*s5.z + a5.w*s5.w
                + a6.x*s6.x + a6.y*s6.y + a6.z*s6.z + a6.w*s6.w
                + a7.x*s7.x + a7.y*s7.y + a7.z*s7.z + a7.w*s7.w;
        }
        accs[k] = acc;
        if (k < 2) BSTG(k + 2);
    }
#undef BSTG
#pragma unroll
    for (int off = 32; off >= 1; off >>= 1) {
#pragma unroll
        for (int k = 0; k < 4; ++k) accs[k] += __shfl_xor(accs[k], off, 64);
    }
    if (lane == 0) {
#pragma unroll
        for (int k = 0; k < 4; ++k)
            vT[(size_t)(d0 + k * 4 + wid) * E_ + e] = accs[k];  // cached
    }

    // c[e] = b1[e,:].w2sum[e,:] + sum_d b2[e,d]   (ws regs still live)
    if ((bid & 63) == 0 && wid == 0) {
        const float4* bp = (const float4*)(b1 + (size_t)e * H_) + lane;
        float4 q0 = bp[0],   q1 = bp[64],  q2 = bp[128], q3 = bp[192],
               q4 = bp[256], q5 = bp[320], q6 = bp[384], q7 = bp[448];
        float s = q0.x*s0.x + q0.y*s0.y + q0.z*s0.z + q0.w*s0.w
                + q1.x*s1.x + q1.y*s1.y + q1.z*s1.z + q1.w*s1.w
                + q2.x*s2.x + q2.y*s2.y + q2.z*s2.z + q2.w*s2.w
                + q3.x*s3.x + q3.y*s3.y + q3.z*s3.z + q3.w*s3.w
                + q4.x*s4.x + q4.y*s4.y + q4.z*s4.z + q4.w*s4.w
                + q5.x*s5.x + q5.y*s5.y + q5.z*s5.z + q5.w*s5.w
                + q6.x*s6.x + q6.y*s6.y + q6.z*s6.z + q6.w*s6.w
                + q7.x*s7.x + q7.y*s7.y + q7.z*s7.z + q7.w*s7.w;
        const float4* cp = (const float4*)(b2 + (size_t)e * D_) + lane;
#pragma unroll
        for (int j = 0; j < 4; ++j) {
            float4 bb = cp[j * 64];
            s += bb.x + bb.y + bb.z + bb.w;
        }
#pragma unroll
        for (int off = 32; off >= 1; off >>= 1) s += __shfl_xor(s, off, 64);
        if (lane == 0) c[e] = s;
    }
}

// --------------------------------------------------------------------------
// Kernel CD: gating + collapsed expert sum, 2 tokens/wave with the PROVEN
// coalesced mapping d = lane + 64*k (wg/vT lane-stride 32 B — round 2-8
// pattern; round 11's lane*4 mapping was a 4x request amplification).
// Last block (counter) then computes the per-batch-row log-softmax.
// 512 blocks x 256 thr.
// --------------------------------------------------------------------------
__global__ __launch_bounds__(256) void cd_kernel(
    const float* __restrict__ x,  const float* __restrict__ wg,
    const float* __restrict__ vT, const float* __restrict__ cbuf,
    float* __restrict__ sbuf, unsigned* __restrict__ ccnt,
    float* __restrict__ out)
{
    const int wid  = threadIdx.x >> 6;
    const int lane = threadIdx.x & 63;
    const int n0   = (blockIdx.x * 4 + wid) * 2;
    const float* x0 = x + (size_t)n0 * D_;
    const float* x1 = x0 + D_;

    float lgA[E_] = {0,0,0,0,0,0,0,0}, dvA[E_] = {0,0,0,0,0,0,0,0};
    float lgB[E_] = {0,0,0,0,0,0,0,0}, dvB[E_] = {0,0,0,0,0,0,0,0};

#pragma unroll
    for (int k = 0; k < D_ / 64; ++k) {                 // 16 iters, coalesced
        const int d = lane + 64 * k;
        float xa = x0[d];
        float xb = x1[d];
        const float4* wgp = (const float4*)(wg + (size_t)d * E_);
        const float4* vp  = (const float4*)(vT + (size_t)d * E_);
        float4 g0 = wgp[0], g1 = wgp[1];
        float4 v0 = vp[0],  v1 = vp[1];
        lgA[0] += xa * g0.x; lgA[1] += xa * g0.y; lgA[2] += xa * g0.z; lgA[3] += xa * g0.w;
        lgA[4] += xa * g1.x; lgA[5] += xa * g1.y; lgA[6] += xa * g1.z; lgA[7] += xa * g1.w;
        dvA[0] += xa * v0.x; dvA[1] += xa * v0.y; dvA[2] += xa * v0.z; dvA[3] += xa * v0.w;
        dvA[4] += xa * v1.x; dvA[5] += xa * v1.y; dvA[6] += xa * v1.z; dvA[7] += xa * v1.w;
        lgB[0] += xb * g0.x; lgB[1] += xb * g0.y; lgB[2] += xb * g0.z; lgB[3] += xb * g0.w;
        lgB[4] += xb * g1.x; lgB[5] += xb * g1.y; lgB[6] += xb * g1.z; lgB[7] += xb * g1.w;
        dvB[0] += xb * v0.x; dvB[1] += xb * v0.y; dvB[2] += xb * v0.z; dvB[3] += xb * v0.w;
        dvB[4] += xb * v1.x; dvB[5] += xb * v1.y; dvB[6] += xb * v1.z; dvB[7] += xb * v1.w;
    }

#pragma unroll
    for (int off = 32; off >= 1; off >>= 1) {
#pragma unroll
        for (int q = 0; q < E_; ++q) {
            lgA[q] += __shfl_xor(lgA[q], off, 64);
            dvA[q] += __shfl_xor(dvA[q], off, 64);
            lgB[q] += __shfl_xor(lgB[q], off, 64);
            dvB[q] += __shfl_xor(dvB[q], off, 64);
        }
    }

    if (lane == 0 || lane == 32) {
        const bool isA = (lane == 0);
        float lg[E_], dvr[E_];
#pragma unroll
        for (int q = 0; q < E_; ++q) {
            lg[q]  = isA ? lgA[q] : lgB[q];
            dvr[q] = isA ? dvA[q] : dvB[q];
        }
        // top-2, tie -> lower index (jax.lax.top_k semantics)
        float m0 = lg[0]; int i0 = 0;
#pragma unroll
        for (int q = 1; q < E_; ++q) if (lg[q] > m0) { m0 = lg[q]; i0 = q; }
        float m1 = -3.0e38f; int i1 = 0;
#pragma unroll
        for (int q = 0; q < E_; ++q) if (q != i0 && lg[q] > m1) { m1 = lg[q]; i1 = q; }
        float dv0 = 0.f, dv1 = 0.f, c0v = 0.f, c1v = 0.f;
#pragma unroll
        for (int q = 0; q < E_; ++q) {
            if (q == i0) { dv0 += dvr[q]; c0v += cbuf[q]; }
            if (q == i1) { dv1 += dvr[q]; c1v += cbuf[q]; }
        }
        float g1w = 1.f / (1.f + expf(m0 - m1));
        AS(&sbuf[isA ? n0 : (n0 + 1)], (1.f - g1w) * (dv0 + c0v) + g1w * (dv1 + c1v));
    }

    // last-block handoff
    asm volatile("s_waitcnt vmcnt(0)" ::: "memory");
    __syncthreads();
    __shared__ int islast;
    if (threadIdx.x == 0) {
        unsigned old = __hip_atomic_fetch_add(ccnt, 1u, __ATOMIC_RELAXED, __HIP_MEMORY_SCOPE_AGENT);
        islast = (old == (unsigned)(gridDim.x - 1)) ? 1 : 0;
    }
    __syncthreads();
    if (!islast) return;

    {   // Phase D: 4 waves, one batch row each; batched sc16 sbuf reads
        const int brow = wid;
        const float* row = sbuf + (size_t)brow * T_;
        float4 v0, v1, v2, v3;
        load4x16_sc(row + lane * 4 + 0 * 256, row + lane * 4 + 1 * 256,
                    row + lane * 4 + 2 * 256, row + lane * 4 + 3 * 256,
                    v0, v1, v2, v3);
        float vals[16] = {v0.x, v0.y, v0.z, v0.w, v1.x, v1.y, v1.z, v1.w,
                          v2.x, v2.y, v2.z, v2.w, v3.x, v3.y, v3.z, v3.w};
        float mx = -3.0e38f;
#pragma unroll
        for (int k = 0; k < 16; ++k) mx = fmaxf(mx, vals[k]);
#pragma unroll
        for (int off = 32; off >= 1; off >>= 1) mx = fmaxf(mx, __shfl_xor(mx, off, 64));
        float sm = 0.f;
#pragma unroll
        for (int k = 0; k < 16; ++k) sm += expf(vals[k] - mx);
#pragma unroll
        for (int off = 32; off >= 1; off >>= 1) sm += __shfl_xor(sm, off, 64);
        float lse = mx + logf(sm);
        // vals[k] order: k = j*4+c maps to t = lane*4 + j*256 + c
#pragma unroll
        for (int j = 0; j < 4; ++j) {
            float4 o;
            o.x = vals[j * 4 + 0] - lse; o.y = vals[j * 4 + 1] - lse;
            o.z = vals[j * 4 + 2] - lse; o.w = vals[j * 4 + 3] - lse;
            *(float4*)&out[(size_t)brow * T_ + lane * 4 + j * 256] = o;
        }
    }
}

// ---------------------------------------------------------------------------
extern "C" void kernel_launch(void* const* d_in, const int* in_sizes, int n_in,
                              void* d_out, int out_size, void* d_ws, size_t ws_size,
                              hipStream_t stream) {
    const float* x  = (const float*)d_in[0];   // [B, T, D]
    const float* wg = (const float*)d_in[1];   // [D, E]
    const float* w1 = (const float*)d_in[2];   // [E, D, H]
    const float* b1 = (const float*)d_in[3];   // [E, H]
    const float* w2 = (const float*)d_in[4];   // [E, H, D]
    const float* b2 = (const float*)d_in[5];   // [E, D]
    float* out = (float*)d_out;                // [B, T]

    float* ws     = (float*)d_ws;
    float* w2sum  = ws;                        // E*H = 16384 floats
    float* vT     = ws + 16384;                // D*E =  8192 floats ([D][E])
    float* cbuf   = ws + 24576;                // E
    float* sbuf   = ws + 24592;                // N = 4096
    unsigned* cnt = (unsigned*)(ws + 28688);   // ccnt

    // zero the CD completion counter (4 B memset node, graph-capturable)
    hipMemsetAsync(cnt, 0, sizeof(unsigned), stream);

    // A: 16384 rows, 32 rows/block (8-tile rolling pipeline) -> 512 blocks
    w2sum_kernel<<<dim3(512), dim3(256), 0, stream>>>(w2, w2sum);
    // B: 8192 rows, 16 rows/block (4-tile rolling pipeline) -> 512 blocks
    v_build_kernel<<<dim3(512), dim3(256), 0, stream>>>(w1, w2sum, b1, b2, vT, cbuf);
    // CD: 4096 tokens, 2/wave -> 512 blocks; last block does log-softmax
    cd_kernel<<<dim3(512), dim3(256), 0, stream>>>(x, wg, vT, cbuf, sbuf, cnt, out);
}